// Round 18
// baseline (210.435 us; speedup 1.0000x reference)
//
#include <hip/hip_runtime.h>
#include <math.h>

#define N_ROWS   65536
#define DIM      256
#define KCODES   1024
#define Q_SIZE   (N_ROWS * DIM)          // 16777216
#define OUT_LOSS Q_SIZE
#define OUT_PERP (Q_SIZE + 1)
#define OUT_IDX  (Q_SIZE + 2)

// flag threshold in scaled-score units (s' = 2^20 * d2-units). Same as r8 (passed).
#define TAUP 200.0f

// ws layout (bytes)
#define WS_LOSS   0        // double
#define WS_RCNT   8        // int
#define WS_E2     16       // float[1024]  original units
#define WS_E2P    4112     // float[1024]  scaled by 2^20
#define WS_COUNTS 8208     // int[1024]
#define WS_IDX    12304    // int[65536]
#define WS_RLIST  274448   // int[65536]
#define WS_ET     536592   // float[262144]   E^T fp32 (refine)
#define WS_P      1585168  // _Float16[262144] packed f16(1024*E) per-wave linear
#define WS_PK     2109456  // u64[65536] per-row (d2,idx) keys — old EL slot, proven ws size

typedef _Float16 half8 __attribute__((ext_vector_type(8)));
typedef _Float16 half4 __attribute__((ext_vector_type(4)));
typedef float    f32x4 __attribute__((ext_vector_type(4)));

#define ROWB 528    // LDS bytes per X row: 512 (xh) + 16 pad
#define RPB  64     // rows per block (r12-proven geometry)

// k_main LDS carve: X 33792 | e2p 4096 = 37888 B (B in registers)
#define LDS_X  0
#define LDS_E2 33792

// ---------------------------------------------------------------------------
// prep: e2, e2p, Et (fp32 transpose, refine), packed P; zero accums.
// P layout: P[q][cb][kk][nt][lane][8 halfs] — per-quarter linear B-frag stream.
// grid 1024 x 256
__global__ void k_prep(const float* __restrict__ E, float* __restrict__ e2,
                       float* __restrict__ e2p, float* __restrict__ Et,
                       _Float16* __restrict__ P,
                       int* __restrict__ counts, double* __restrict__ loss,
                       int* __restrict__ rcnt) {
    int b = blockIdx.x, t = threadIdx.x;
    __shared__ double red[256];
    float v = E[b * DIM + t];
    red[t] = (double)v * (double)v;

    {   // packed B-stream write
        int o   = b * 256 + t;
        int j    = o & 7;
        int lane = (o >> 3) & 63;
        int nt   = (o >> 9) & 3;
        int kk   = (o >> 11) & 7;
        int cbq  = o >> 14;            // 0..15
        int q = cbq >> 2, cb = cbq & 3;
        int code = q * 256 + cb * 64 + nt * 16 + (lane & 15);
        int d    = (lane >> 4) * 8 + kk * 32 + j;
        P[o] = (_Float16)(E[code * DIM + d] * 1024.0f);   // exact scaling, RN
    }

    __syncthreads();
    for (int s = 128; s > 0; s >>= 1) {
        if (t < s) red[t] += red[t + s];
        __syncthreads();
    }
    if (t == 0) { e2[b] = (float)red[0]; e2p[b] = (float)(red[0] * 1048576.0); }

    int o = b * 256 + t;
    int d = o >> 10, k = o & 1023;
    Et[o] = E[k * DIM + d];

    if (b < 4) counts[b * 256 + t] = 0;
    if (b == 0 && t == 0) { *loss = 0.0; *rcnt = 0; }
}

// ---------------------------------------------------------------------------
// main: r12-exact structure + (a) NT X staging (clean single-kernel A/B vs
// r12's 87µs — theory: X streams evict the 512KB P set from L2, forcing
// L3-rate P re-fetches ≈ 5.9 TB/s aggregate), (b) pk[row] init at flag time
// for the new slice-refine. Numerics bit-identical to r8-r17.
// V0-style mod-3 depth-2 register pipeline, counted vmcnt(8).
// OCCUPANCY NOTE (r4-r7,r16): never cap waves / use 512-thr blocks — spills.
// grid 1024 x 256
__global__ void __launch_bounds__(256)
k_main(const float* __restrict__ X, const _Float16* __restrict__ P,
       const float* __restrict__ e2p,
       int* __restrict__ idx_ws, int* __restrict__ rlist,
       int* __restrict__ rcnt, unsigned long long* __restrict__ pk) {
    __shared__ __align__(16) char sAll[37888];
    const int tid  = threadIdx.x;
    const int wid  = tid >> 6;
    const int lane = tid & 63;
    const int c16  = lane & 15;
    const int kg   = lane >> 4;
    const int rb   = blockIdx.x * RPB;

    char* sA = sAll + LDS_X;

    // ---- stage X -> f16 in LDS (non-temporal reads); stage e2p -> LDS ----
    {
        const f32x4* Xg = (const f32x4*)(X + (size_t)rb * DIM);
        #pragma unroll
        for (int it = 0; it < 16; ++it) {
            int f = it * 256 + tid;
            int row = f >> 6, d4 = f & 63;
            f32x4 v = __builtin_nontemporal_load(&Xg[(size_t)row * 64 + d4]);
            half4 hh = {(_Float16)v[0], (_Float16)v[1], (_Float16)v[2], (_Float16)v[3]};
            *(half4*)(sA + row * ROWB + d4 * 8) = hh;
        }
        ((f32x4*)(sAll + LDS_E2))[tid] = ((const f32x4*)e2p)[tid];
    }
    __syncthreads();   // drains staging vmem — in-loop vmcnt counts only B loads

    // per-wave contiguous B stream: 128 KB per quarter, lane offset 16B
    const char* gB = (const char*)P + (size_t)wid * 131072 + (size_t)lane * 16;
#define GLOADC(dst, c)                                                        \
    asm volatile("global_load_dwordx4 %0, %1, off"                            \
                 : "=v"(dst)                                                  \
                 : "v"(gB + (size_t)((c) * 1024))                             \
                 : "memory")
#define VMW(n) { asm volatile("s_waitcnt vmcnt(" #n ")" ::: "memory");        \
                 __builtin_amdgcn_sched_barrier(0); }

    int Abase[4];
    #pragma unroll
    for (int mt = 0; mt < 4; ++mt) Abase[mt] = (mt * 16 + c16) * ROWB + kg * 16;

    float tb1[16], tb2[16];
    int   ti1[16];
    #pragma unroll
    for (int i = 0; i < 16; ++i) { tb1[i] = 3.4e38f; tb2[i] = 3.4e38f; ti1[i] = 0; }

    const int cw = wid * 256;
    const float* sE2 = (const float*)(sAll + LDS_E2);

    f32x4 acc[4][4];

    // mod-3 depth-2 register pipeline (r14 V0 structure)
    half8 b[3][4];
    #pragma unroll
    for (int nt = 0; nt < 4; ++nt) GLOADC(b[0][nt], 0 * 4 + nt);
    #pragma unroll
    for (int nt = 0; nt < 4; ++nt) GLOADC(b[1][nt], 1 * 4 + nt);

    #pragma unroll
    for (int s = 0; s < 32; ++s) {
        const int kk = s & 7;
        if (kk == 0) {
            #pragma unroll
            for (int mt = 0; mt < 4; ++mt)
                #pragma unroll
                for (int nt = 0; nt < 4; ++nt) acc[mt][nt] = 0.0f;
        }
        if (s <= 29) {
            #pragma unroll
            for (int nt = 0; nt < 4; ++nt) GLOADC(b[(s + 2) % 3][nt], (s + 2) * 4 + nt);
        }
        if (s <= 29)      VMW(8)
        else if (s == 30) VMW(4)
        else              VMW(0)

        half8 ah[4];
        #pragma unroll
        for (int mt = 0; mt < 4; ++mt)
            ah[mt] = *(const half8*)(sA + Abase[mt] + kk * 64);

        #pragma unroll
        for (int mt = 0; mt < 4; ++mt) {
            acc[mt][0] = __builtin_amdgcn_mfma_f32_16x16x32_f16(ah[mt], b[s % 3][0], acc[mt][0], 0, 0, 0);
            acc[mt][1] = __builtin_amdgcn_mfma_f32_16x16x32_f16(ah[mt], b[s % 3][1], acc[mt][1], 0, 0, 0);
            acc[mt][2] = __builtin_amdgcn_mfma_f32_16x16x32_f16(ah[mt], b[s % 3][2], acc[mt][2], 0, 0, 0);
            acc[mt][3] = __builtin_amdgcn_mfma_f32_16x16x32_f16(ah[mt], b[s % 3][3], acc[mt][3], 0, 0, 0);
        }

        if (kk == 7) {
            const int cb = s >> 3;
            const int cbase = cw + cb * 64;
            const int c0 = cbase + c16;
            float e2v[4];
            #pragma unroll
            for (int nt = 0; nt < 4; ++nt) e2v[nt] = sE2[c0 + nt * 16];
            #pragma unroll
            for (int mt = 0; mt < 4; ++mt)
                #pragma unroll
                for (int nt = 0; nt < 4; ++nt) {
                    int code = cbase + nt * 16 + c16;
                    #pragma unroll
                    for (int r = 0; r < 4; ++r) {
                        float sc = fmaf(-2048.0f, acc[mt][nt][r], e2v[nt]);
                        int ix = mt * 4 + r;
                        tb2[ix] = __builtin_amdgcn_fmed3f(tb1[ix], tb2[ix], sc);
                        bool lt = sc < tb1[ix];
                        tb1[ix] = lt ? sc : tb1[ix];
                        ti1[ix] = lt ? code : ti1[ix];
                    }
                }
        }
    }
#undef GLOADC
#undef VMW

    // ---- butterfly merge across the 16 col-lanes of each kg group ----
    #pragma unroll
    for (int ix = 0; ix < 16; ++ix) {
        float v1 = tb1[ix], v2 = tb2[ix];
        int   j1 = ti1[ix];
        #pragma unroll
        for (int m = 1; m < 16; m <<= 1) {
            float ov1 = __shfl_xor(v1, m, 64);
            int   oj1 = __shfl_xor(j1, m, 64);
            float ov2 = __shfl_xor(v2, m, 64);
            bool take = (ov1 < v1) || (ov1 == v1 && oj1 < j1);
            float losr = take ? v1 : ov1;
            v1 = take ? ov1 : v1;
            j1 = take ? oj1 : j1;
            v2 = fminf(fminf(v2, ov2), losr);
        }
        tb1[ix] = v1; tb2[ix] = v2; ti1[ix] = j1;
    }

    // ---- cross-wave merge via LDS (reuse sA region) ----
    __syncthreads();
    float* mB1 = (float*)sA;            // [64][4]
    float* mB2 = (float*)(sA + 1024);   // [64][4]
    int*   mI1 = (int*)(sA + 2048);     // [64][4]
    #pragma unroll
    for (int ix = 0; ix < 16; ++ix) {
        if (c16 == ix) {
            int row = (ix >> 2) * 16 + kg * 4 + (ix & 3);
            mB1[row * 4 + wid] = tb1[ix];
            mB2[row * 4 + wid] = tb2[ix];
            mI1[row * 4 + wid] = ti1[ix];
        }
    }
    __syncthreads();
    if (tid < RPB) {
        float m1 = 3.4e38f, m2 = 3.4e38f;
        int mi = 0;
        #pragma unroll
        for (int w = 0; w < 4; ++w) {
            float v = mB1[tid * 4 + w];
            int  id = mI1[tid * 4 + w];
            float u = mB2[tid * 4 + w];
            bool take = (v < m1) || (v == m1 && id < mi);
            float losr = take ? m1 : v;
            m1 = take ? v : m1;
            mi = take ? id : mi;
            m2 = fminf(fminf(m2, u), losr);
        }
        int g = rb + tid;
        idx_ws[g] = mi;
        if (m2 - m1 < TAUP) {
            int slot = atomicAdd(rcnt, 1);
            rlist[slot] = g;
            pk[g] = 0xFFFFFFFFFFFFFFFFull;   // init key for slice-refine
        }
    }
}

// ---------------------------------------------------------------------------
// rslice (r18): exact fp32-replication refine, restructured. 256 blocks =
// 32 code-slices x 8 row-groups. Block stages its 32-code Et slice in LDS
// once (Et traffic 625MB -> 8MB vs r15) and streams its flagged rows in
// 32-row micro-batches. Per (row,code): M32 = fl32(SERIAL fp64 dot, d asc —
// identical order to all passing rounds); d2 = fmaf(-2,M32,x2+e2). Winner
// merged chip-wide via atomicMin on key = ordered(d2)<<32 | idx (lexicographic
// = lowest d2 then lowest index, matching numpy argmin).
// grid 256 x 256
__global__ void __launch_bounds__(256)
k_rslice(const float* __restrict__ X, const float* __restrict__ Et,
         const float* __restrict__ e2,
         const int* __restrict__ rlist, const int* __restrict__ rcnt,
         unsigned long long* __restrict__ pk) {
    __shared__ float  Esl[256][32];   // [d][c] 32KB
    __shared__ float  e2s[32];
    __shared__ float  xs[32][260];    // 32 rows, padded (q-lanes conflict-free)
    __shared__ double red[256];
    __shared__ float  x2s[32];
    __shared__ int    rows[32];
    const int cnt = *rcnt;
    if (cnt == 0) return;
    const int t  = threadIdx.x;
    const int sl = blockIdx.x & 31;   // code slice: codes sl*32 .. sl*32+31
    const int rg = blockIdx.x >> 5;   // row group: e ≡ rg (mod 8)

    // stage Et slice (coalesced 32-float runs) + e2 slice
    #pragma unroll
    for (int i = 0; i < 32; ++i) {
        int idx = i * 256 + t;
        int d = idx >> 5, c = idx & 31;
        Esl[d][c] = Et[d * KCODES + sl * 32 + c];
    }
    if (t < 32) e2s[t] = e2[sl * 32 + t];

    const int c8 = t & 7;             // code sub-group (4 codes each)
    const int q  = t >> 3;            // row 0..31 within micro-batch

    for (int j0 = 0; rg + 8 * j0 < cnt; j0 += 32) {
        __syncthreads();
        if (t < 32) {
            int e = rg + 8 * (j0 + t);
            rows[t] = rlist[e < cnt ? e : (cnt - 1)];
        }
        __syncthreads();
        // stage 32 rows of X (2048 float4 slots -> 8 per thread)
        #pragma unroll
        for (int i = 0; i < 8; ++i) {
            int slot = i * 256 + t;
            int r = slot >> 6, c4 = slot & 63;
            *(f32x4*)&xs[r][c4 * 4] =
                *(const f32x4*)(X + (size_t)rows[r] * DIM + c4 * 4);
        }
        __syncthreads();
        // x2_32 per row: fp64 partial (t = r*8 + k8 over d-segments) + serial tail
        {
            int rr = t >> 3, k8 = t & 7;
            double s = 0.0;
            #pragma unroll 8
            for (int d = k8 * 32; d < k8 * 32 + 32; ++d) {
                double xv = (double)xs[rr][d];
                s += xv * xv;
            }
            red[t] = s;
            __syncthreads();
            if (t < 32) {
                double s2 = 0.0;
                #pragma unroll
                for (int i = 0; i < 8; ++i) s2 += red[t * 8 + i];
                x2s[t] = (float)s2;
            }
            __syncthreads();
        }

        // serial fp64 dots: thread (q,c8) -> row q, codes sl*32+c8*4..+3
        double a0 = 0.0, a1 = 0.0, a2 = 0.0, a3 = 0.0;
        #pragma unroll 4
        for (int d = 0; d < DIM; ++d) {
            f32x4 ev = *(const f32x4*)&Esl[d][c8 * 4];
            double xv = (double)xs[q][d];
            a0 += xv * (double)ev[0];
            a1 += xv * (double)ev[1];
            a2 += xv * (double)ev[2];
            a3 += xv * (double)ev[3];
        }

        // fp32-replicated scores + per-thread best (ascending code = lowest idx)
        float x2 = x2s[q];
        float best = 3.4e38f; int bk = 0;
        {
            float d2 = fmaf(-2.f, (float)a0, x2 + e2s[c8 * 4 + 0]);
            if (d2 < best) { best = d2; bk = sl * 32 + c8 * 4 + 0; }
        }
        {
            float d2 = fmaf(-2.f, (float)a1, x2 + e2s[c8 * 4 + 1]);
            if (d2 < best) { best = d2; bk = sl * 32 + c8 * 4 + 1; }
        }
        {
            float d2 = fmaf(-2.f, (float)a2, x2 + e2s[c8 * 4 + 2]);
            if (d2 < best) { best = d2; bk = sl * 32 + c8 * 4 + 2; }
        }
        {
            float d2 = fmaf(-2.f, (float)a3, x2 + e2s[c8 * 4 + 3]);
            if (d2 < best) { best = d2; bk = sl * 32 + c8 * 4 + 3; }
        }
        // reduce over the 8 c8-lanes of this row (lanes share q = lane>>3)
        #pragma unroll
        for (int m = 1; m < 8; m <<= 1) {
            float ov = __shfl_xor(best, m, 64);
            int   oi = __shfl_xor(bk, m, 64);
            if (ov < best || (ov == best && oi < bk)) { best = ov; bk = oi; }
        }
        if (c8 == 0) {
            int e = rg + 8 * (j0 + q);
            if (e < cnt) {
                unsigned int u = __float_as_uint(best);
                u = (u & 0x80000000u) ? ~u : (u | 0x80000000u);
                unsigned long long key = ((unsigned long long)u << 32) | (unsigned int)bk;
                atomicMin(&pk[rows[q]], key);
            }
        }
    }
}

// ---------------------------------------------------------------------------
// rfinal: write merged winners to idx_ws. grid 256 x 256
__global__ void k_rfinal(const int* __restrict__ rlist, const int* __restrict__ rcnt,
                         const unsigned long long* __restrict__ pk,
                         int* __restrict__ idx_ws) {
    int e = blockIdx.x * 256 + threadIdx.x;
    if (e < *rcnt) {
        int row = rlist[e];
        idx_ws[row] = (int)(pk[row] & 0xFFFFFFFFull);
    }
}

// ---------------------------------------------------------------------------
// out: quantized rows, index output, loss, histogram. One fp64 atomic/block.
// grid 1024 x 256
__launch_bounds__(256)
__global__ void k_out(const float* __restrict__ X, const float* __restrict__ E,
                      const int* __restrict__ idx_ws, float* __restrict__ out,
                      int* __restrict__ counts, double* __restrict__ loss) {
    const int tid = threadIdx.x;
    const int w = tid >> 6, lane = tid & 63;
    const int rbase = blockIdx.x * 64;
    double ls = 0.0;
    #pragma unroll 4
    for (int it = 0; it < 16; ++it) {
        const int row = rbase + it * 4 + w;
        const int k = idx_ws[row];
        float4 q = ((const float4*)(E + (size_t)k * DIM))[lane];
        float4 x = ((const float4*)(X + (size_t)row * DIM))[lane];
        ((float4*)(out + (size_t)row * DIM))[lane] = q;
        double d0 = (double)q.x - (double)x.x;
        double d1 = (double)q.y - (double)x.y;
        double d2 = (double)q.z - (double)x.z;
        double d3 = (double)q.w - (double)x.w;
        ls += d0 * d0 + d1 * d1 + d2 * d2 + d3 * d3;
        if (lane == 0) {
            atomicAdd(&counts[k], 1);
            out[OUT_IDX + row] = (float)k;
        }
    }
    __shared__ double red[256];
    red[tid] = ls;
    __syncthreads();
    for (int s = 128; s > 0; s >>= 1) {
        if (tid < s) red[tid] += red[tid + s];
        __syncthreads();
    }
    if (tid == 0) atomicAdd(loss, red[0]);
}

// ---------------------------------------------------------------------------
// fin: scalars
__global__ void k_fin(const int* __restrict__ counts, const double* __restrict__ loss,
                      float* __restrict__ out) {
    int t = threadIdx.x;
    __shared__ double red[256];
    double h = 0.0;
    #pragma unroll
    for (int i = 0; i < 4; ++i) {
        double p = (double)counts[t + i * 256] / (double)N_ROWS;
        h += p * log(p + 1e-10);
    }
    red[t] = h;
    __syncthreads();
    for (int s = 128; s > 0; s >>= 1) {
        if (t < s) red[t] += red[t + s];
        __syncthreads();
    }
    if (t == 0) {
        out[OUT_PERP] = (float)exp(-red[0]);
        out[OUT_LOSS] = (float)((*loss) / (double)Q_SIZE * 1.25);
    }
}

// ---------------------------------------------------------------------------
extern "C" void kernel_launch(void* const* d_in, const int* in_sizes, int n_in,
                              void* d_out, int out_size, void* d_ws, size_t ws_size,
                              hipStream_t stream) {
    (void)in_sizes; (void)n_in; (void)out_size; (void)ws_size;
    const float* X = (const float*)d_in[0];
    const float* E = (const float*)d_in[1];
    float* out = (float*)d_out;
    char* ws = (char*)d_ws;

    double*             loss   = (double*)(ws + WS_LOSS);
    int*                rcnt   = (int*)(ws + WS_RCNT);
    float*              e2     = (float*)(ws + WS_E2);
    float*              e2p    = (float*)(ws + WS_E2P);
    int*                counts = (int*)(ws + WS_COUNTS);
    int*                idx_ws = (int*)(ws + WS_IDX);
    int*                rlist  = (int*)(ws + WS_RLIST);
    float*              Et     = (float*)(ws + WS_ET);
    _Float16*           Pp     = (_Float16*)(ws + WS_P);
    unsigned long long* pk     = (unsigned long long*)(ws + WS_PK);

    k_prep<<<1024, 256, 0, stream>>>(E, e2, e2p, Et, Pp, counts, loss, rcnt);
    k_main<<<N_ROWS / RPB, 256, 0, stream>>>(X, Pp, e2p, idx_ws, rlist, rcnt, pk);
    k_rslice<<<256, 256, 0, stream>>>(X, Et, e2, rlist, rcnt, pk);
    k_rfinal<<<256, 256, 0, stream>>>(rlist, rcnt, pk, idx_ws);
    k_out<<<1024, 256, 0, stream>>>(X, E, idx_ws, out, counts, loss);
    k_fin<<<1, 256, 0, stream>>>(counts, loss, out);
}

// Round 19
// 171.527 us; speedup vs baseline: 1.2268x; 1.2268x over previous
//
#include <hip/hip_runtime.h>
#include <math.h>

#define N_ROWS   65536
#define DIM      256
#define KCODES   1024
#define Q_SIZE   (N_ROWS * DIM)          // 16777216
#define OUT_LOSS Q_SIZE
#define OUT_PERP (Q_SIZE + 1)
#define OUT_IDX  (Q_SIZE + 2)

// flag threshold in scaled-score units (s' = 2^20 * d2-units). Same as r8 (passed).
#define TAUP 200.0f

// ws layout (bytes)
#define WS_LOSS   0        // double
#define WS_RCNT   8        // int
#define WS_E2     16       // float[1024]  original units
#define WS_E2P    4112     // float[1024]  scaled by 2^20
#define WS_COUNTS 8208     // int[1024]
#define WS_IDX    12304    // int[65536]
#define WS_RLIST  274448   // int[65536]
#define WS_ET     536592   // float[262144]   E^T fp32 (refine)
#define WS_P      1585168  // _Float16[262144] packed f16(1024*E) per-wave linear

typedef _Float16 half8 __attribute__((ext_vector_type(8)));
typedef _Float16 half4 __attribute__((ext_vector_type(4)));
typedef float    f32x4 __attribute__((ext_vector_type(4)));

#define ROWB 528    // LDS bytes per X row: 512 (xh) + 16 pad
#define RPB  64     // rows per block (r12-proven geometry)

// k_main LDS carve: X 33792 | e2p 4096 = 37888 B (B in registers)
#define LDS_X  0
#define LDS_E2 33792

// ---------------------------------------------------------------------------
// prep: e2, e2p, Et (fp32 transpose, refine), packed P; zero accums.
// P layout: P[q][cb][kk][nt][lane][8 halfs] — per-quarter linear B-frag stream.
// grid 1024 x 256
__global__ void k_prep(const float* __restrict__ E, float* __restrict__ e2,
                       float* __restrict__ e2p, float* __restrict__ Et,
                       _Float16* __restrict__ P,
                       int* __restrict__ counts, double* __restrict__ loss,
                       int* __restrict__ rcnt) {
    int b = blockIdx.x, t = threadIdx.x;
    __shared__ double red[256];
    float v = E[b * DIM + t];
    red[t] = (double)v * (double)v;

    {   // packed B-stream write
        int o   = b * 256 + t;
        int j    = o & 7;
        int lane = (o >> 3) & 63;
        int nt   = (o >> 9) & 3;
        int kk   = (o >> 11) & 7;
        int cbq  = o >> 14;            // 0..15
        int q = cbq >> 2, cb = cbq & 3;
        int code = q * 256 + cb * 64 + nt * 16 + (lane & 15);
        int d    = (lane >> 4) * 8 + kk * 32 + j;
        P[o] = (_Float16)(E[code * DIM + d] * 1024.0f);   // exact scaling, RN
    }

    __syncthreads();
    for (int s = 128; s > 0; s >>= 1) {
        if (t < s) red[t] += red[t + s];
        __syncthreads();
    }
    if (t == 0) { e2[b] = (float)red[0]; e2p[b] = (float)(red[0] * 1048576.0); }

    int o = b * 256 + t;
    int d = o >> 10, k = o & 1023;
    Et[o] = E[k * DIM + d];

    if (b < 4) counts[b * 256 + t] = 0;
    if (b == 0 && t == 0) { *loss = 0.0; *rcnt = 0; }
}

// ---------------------------------------------------------------------------
// main: r12-exact structure; r19 fix: B-load asm has NO "memory" clobber.
// THEORY (explains the 21µs/block constant across r10-r15): the "memory"
// clobber made the compiler order each load group against the NEXT step's
// A-frag ds_reads by draining vmcnt(0) every step — one full L2 round-trip
// per step (~1570cyc ✓). Without the clobber, dataflow is carried by "=v"
// and ordering solely by our counted VMW(8) + sched_barrier(0) — the
// intended depth-2 pipeline finally exists at ISA level.
// Numerics bit-identical to r8-r18. NT X-staging kept (r18).
// OCCUPANCY NOTE (r4-r7,r16): never cap waves / 512-thr blocks — spills.
// grid 1024 x 256
__global__ void __launch_bounds__(256)
k_main(const float* __restrict__ X, const _Float16* __restrict__ P,
       const float* __restrict__ e2p,
       int* __restrict__ idx_ws, int* __restrict__ rlist,
       int* __restrict__ rcnt) {
    __shared__ __align__(16) char sAll[37888];
    const int tid  = threadIdx.x;
    const int wid  = tid >> 6;
    const int lane = tid & 63;
    const int c16  = lane & 15;
    const int kg   = lane >> 4;
    const int rb   = blockIdx.x * RPB;

    char* sA = sAll + LDS_X;

    // ---- stage X -> f16 in LDS (non-temporal reads); stage e2p -> LDS ----
    {
        const f32x4* Xg = (const f32x4*)(X + (size_t)rb * DIM);
        #pragma unroll
        for (int it = 0; it < 16; ++it) {
            int f = it * 256 + tid;
            int row = f >> 6, d4 = f & 63;
            f32x4 v = __builtin_nontemporal_load(&Xg[(size_t)row * 64 + d4]);
            half4 hh = {(_Float16)v[0], (_Float16)v[1], (_Float16)v[2], (_Float16)v[3]};
            *(half4*)(sA + row * ROWB + d4 * 8) = hh;
        }
        ((f32x4*)(sAll + LDS_E2))[tid] = ((const f32x4*)e2p)[tid];
    }
    __syncthreads();   // drains staging vmem — in-loop vmcnt counts only B loads

    // per-wave contiguous B stream: 128 KB per quarter, lane offset 16B
    const char* gB = (const char*)P + (size_t)wid * 131072 + (size_t)lane * 16;
    // NOTE: no "memory" clobber — see kernel comment. volatile keeps each
    // load instance; "=v" carries the dataflow; VMW/sched_barrier pin order.
#define GLOADC(dst, c)                                                        \
    asm volatile("global_load_dwordx4 %0, %1, off"                            \
                 : "=v"(dst)                                                  \
                 : "v"(gB + (size_t)((c) * 1024)))
#define VMW(n) { asm volatile("s_waitcnt vmcnt(" #n ")" ::: "memory");        \
                 __builtin_amdgcn_sched_barrier(0); }

    int Abase[4];
    #pragma unroll
    for (int mt = 0; mt < 4; ++mt) Abase[mt] = (mt * 16 + c16) * ROWB + kg * 16;

    float tb1[16], tb2[16];
    int   ti1[16];
    #pragma unroll
    for (int i = 0; i < 16; ++i) { tb1[i] = 3.4e38f; tb2[i] = 3.4e38f; ti1[i] = 0; }

    const int cw = wid * 256;
    const float* sE2 = (const float*)(sAll + LDS_E2);

    f32x4 acc[4][4];

    // mod-3 depth-2 register pipeline (r14 V0 structure)
    half8 b[3][4];
    #pragma unroll
    for (int nt = 0; nt < 4; ++nt) GLOADC(b[0][nt], 0 * 4 + nt);
    #pragma unroll
    for (int nt = 0; nt < 4; ++nt) GLOADC(b[1][nt], 1 * 4 + nt);
    __builtin_amdgcn_sched_barrier(0);   // pin prologue loads before the loop

    #pragma unroll
    for (int s = 0; s < 32; ++s) {
        const int kk = s & 7;
        if (kk == 0) {
            #pragma unroll
            for (int mt = 0; mt < 4; ++mt)
                #pragma unroll
                for (int nt = 0; nt < 4; ++nt) acc[mt][nt] = 0.0f;
        }
        if (s <= 29) {
            #pragma unroll
            for (int nt = 0; nt < 4; ++nt) GLOADC(b[(s + 2) % 3][nt], (s + 2) * 4 + nt);
        }
        if (s <= 29)      VMW(8)
        else if (s == 30) VMW(4)
        else              VMW(0)

        half8 ah[4];
        #pragma unroll
        for (int mt = 0; mt < 4; ++mt)
            ah[mt] = *(const half8*)(sA + Abase[mt] + kk * 64);

        #pragma unroll
        for (int mt = 0; mt < 4; ++mt) {
            acc[mt][0] = __builtin_amdgcn_mfma_f32_16x16x32_f16(ah[mt], b[s % 3][0], acc[mt][0], 0, 0, 0);
            acc[mt][1] = __builtin_amdgcn_mfma_f32_16x16x32_f16(ah[mt], b[s % 3][1], acc[mt][1], 0, 0, 0);
            acc[mt][2] = __builtin_amdgcn_mfma_f32_16x16x32_f16(ah[mt], b[s % 3][2], acc[mt][2], 0, 0, 0);
            acc[mt][3] = __builtin_amdgcn_mfma_f32_16x16x32_f16(ah[mt], b[s % 3][3], acc[mt][3], 0, 0, 0);
        }

        if (kk == 7) {
            const int cb = s >> 3;
            const int cbase = cw + cb * 64;
            const int c0 = cbase + c16;
            float e2v[4];
            #pragma unroll
            for (int nt = 0; nt < 4; ++nt) e2v[nt] = sE2[c0 + nt * 16];
            #pragma unroll
            for (int mt = 0; mt < 4; ++mt)
                #pragma unroll
                for (int nt = 0; nt < 4; ++nt) {
                    int code = cbase + nt * 16 + c16;
                    #pragma unroll
                    for (int r = 0; r < 4; ++r) {
                        float sc = fmaf(-2048.0f, acc[mt][nt][r], e2v[nt]);
                        int ix = mt * 4 + r;
                        tb2[ix] = __builtin_amdgcn_fmed3f(tb1[ix], tb2[ix], sc);
                        bool lt = sc < tb1[ix];
                        tb1[ix] = lt ? sc : tb1[ix];
                        ti1[ix] = lt ? code : ti1[ix];
                    }
                }
        }
    }
#undef GLOADC
#undef VMW

    // ---- butterfly merge across the 16 col-lanes of each kg group ----
    #pragma unroll
    for (int ix = 0; ix < 16; ++ix) {
        float v1 = tb1[ix], v2 = tb2[ix];
        int   j1 = ti1[ix];
        #pragma unroll
        for (int m = 1; m < 16; m <<= 1) {
            float ov1 = __shfl_xor(v1, m, 64);
            int   oj1 = __shfl_xor(j1, m, 64);
            float ov2 = __shfl_xor(v2, m, 64);
            bool take = (ov1 < v1) || (ov1 == v1 && oj1 < j1);
            float losr = take ? v1 : ov1;
            v1 = take ? ov1 : v1;
            j1 = take ? oj1 : j1;
            v2 = fminf(fminf(v2, ov2), losr);
        }
        tb1[ix] = v1; tb2[ix] = v2; ti1[ix] = j1;
    }

    // ---- cross-wave merge via LDS (reuse sA region) ----
    __syncthreads();
    float* mB1 = (float*)sA;            // [64][4]
    float* mB2 = (float*)(sA + 1024);   // [64][4]
    int*   mI1 = (int*)(sA + 2048);     // [64][4]
    #pragma unroll
    for (int ix = 0; ix < 16; ++ix) {
        if (c16 == ix) {
            int row = (ix >> 2) * 16 + kg * 4 + (ix & 3);
            mB1[row * 4 + wid] = tb1[ix];
            mB2[row * 4 + wid] = tb2[ix];
            mI1[row * 4 + wid] = ti1[ix];
        }
    }
    __syncthreads();
    if (tid < RPB) {
        float m1 = 3.4e38f, m2 = 3.4e38f;
        int mi = 0;
        #pragma unroll
        for (int w = 0; w < 4; ++w) {
            float v = mB1[tid * 4 + w];
            int  id = mI1[tid * 4 + w];
            float u = mB2[tid * 4 + w];
            bool take = (v < m1) || (v == m1 && id < mi);
            float losr = take ? m1 : v;
            m1 = take ? v : m1;
            mi = take ? id : mi;
            m2 = fminf(fminf(m2, u), losr);
        }
        int g = rb + tid;
        idx_ws[g] = mi;
        if (m2 - m1 < TAUP) {
            int slot = atomicAdd(rcnt, 1);
            rlist[slot] = g;
        }
    }
}

// ---------------------------------------------------------------------------
// refine: exact reference-fp32 replication, 4 rows per Et sweep, d-loop
// unrolled x4, grid 1024 (r12/r13-proven). fp64 accumulation order per
// accumulator UNCHANGED.
// grid 1024 x 256
__launch_bounds__(256, 1)
__global__ void k_refine(const float* __restrict__ X, const float* __restrict__ Et,
                         const float* __restrict__ e2,
                         const int* __restrict__ rlist, const int* __restrict__ rcnt,
                         int* __restrict__ idx_ws) {
    __shared__ float xs[4][256];
    __shared__ float sbv[4][256];
    __shared__ int   sbi[4][256];
    __shared__ float x2s[4];
    __shared__ int   rows[4];
    const int cnt = *rcnt;
    const int t = threadIdx.x;
    for (int base = blockIdx.x * 4; base < cnt; base += gridDim.x * 4) {
        __syncthreads();
        if (t < 4) {
            int e = base + t;
            rows[t] = rlist[e < cnt ? e : (cnt - 1)];
        }
        __syncthreads();
        ((float4*)xs[t >> 6])[t & 63] =
            ((const float4*)(X + (size_t)rows[t >> 6] * DIM))[t & 63];
        __syncthreads();
        if (t < 4) {
            double s = 0.0;
            for (int d = 0; d < DIM; ++d) { double xv = (double)xs[t][d]; s += xv * xv; }
            x2s[t] = (float)s;
        }
        __syncthreads();

        double a0[4], a1[4], a2[4], a3[4];
        #pragma unroll
        for (int r = 0; r < 4; ++r) { a0[r] = 0.0; a1[r] = 0.0; a2[r] = 0.0; a3[r] = 0.0; }
        #pragma unroll 4
        for (int d = 0; d < DIM; ++d) {
            double e0 = (double)Et[d * KCODES + t];
            double e1 = (double)Et[d * KCODES + 256 + t];
            double e2d = (double)Et[d * KCODES + 512 + t];
            double e3 = (double)Et[d * KCODES + 768 + t];
            #pragma unroll
            for (int r = 0; r < 4; ++r) {
                double xv = (double)xs[r][d];
                a0[r] += xv * e0;
                a1[r] += xv * e1;
                a2[r] += xv * e2d;
                a3[r] += xv * e3;
            }
        }

        const float eA = e2[t], eB = e2[256 + t], eC = e2[512 + t], eD = e2[768 + t];
        #pragma unroll
        for (int r = 0; r < 4; ++r) {
            float best = 3.4e38f; int bk = 0;
            float x2 = x2s[r];
            { float d2 = fmaf(-2.f, (float)a0[r], x2 + eA); if (d2 < best) { best = d2; bk = t; } }
            { float d2 = fmaf(-2.f, (float)a1[r], x2 + eB); if (d2 < best) { best = d2; bk = 256 + t; } }
            { float d2 = fmaf(-2.f, (float)a2[r], x2 + eC); if (d2 < best) { best = d2; bk = 512 + t; } }
            { float d2 = fmaf(-2.f, (float)a3[r], x2 + eD); if (d2 < best) { best = d2; bk = 768 + t; } }
            sbv[r][t] = best; sbi[r][t] = bk;
        }
        __syncthreads();
        {
            const int w = t >> 6, lane = t & 63;
            float v = sbv[w][lane];     int id = sbi[w][lane];
            #pragma unroll
            for (int c = 1; c < 4; ++c) {
                float ov = sbv[w][lane + 64 * c]; int oi = sbi[w][lane + 64 * c];
                if (ov < v || (ov == v && oi < id)) { v = ov; id = oi; }
            }
            #pragma unroll
            for (int m = 1; m < 64; m <<= 1) {
                float ov = __shfl_xor(v, m, 64);
                int   oi = __shfl_xor(id, m, 64);
                if (ov < v || (ov == v && oi < id)) { v = ov; id = oi; }
            }
            if (lane == 0 && base + w < cnt) idx_ws[rows[w]] = id;
        }
    }
}

// ---------------------------------------------------------------------------
// out: quantized rows, index output, loss, histogram. One fp64 atomic/block.
// grid 1024 x 256
__launch_bounds__(256)
__global__ void k_out(const float* __restrict__ X, const float* __restrict__ E,
                      const int* __restrict__ idx_ws, float* __restrict__ out,
                      int* __restrict__ counts, double* __restrict__ loss) {
    const int tid = threadIdx.x;
    const int w = tid >> 6, lane = tid & 63;
    const int rbase = blockIdx.x * 64;
    double ls = 0.0;
    #pragma unroll 4
    for (int it = 0; it < 16; ++it) {
        const int row = rbase + it * 4 + w;
        const int k = idx_ws[row];
        float4 q = ((const float4*)(E + (size_t)k * DIM))[lane];
        float4 x = ((const float4*)(X + (size_t)row * DIM))[lane];
        ((float4*)(out + (size_t)row * DIM))[lane] = q;
        double d0 = (double)q.x - (double)x.x;
        double d1 = (double)q.y - (double)x.y;
        double d2 = (double)q.z - (double)x.z;
        double d3 = (double)q.w - (double)x.w;
        ls += d0 * d0 + d1 * d1 + d2 * d2 + d3 * d3;
        if (lane == 0) {
            atomicAdd(&counts[k], 1);
            out[OUT_IDX + row] = (float)k;
        }
    }
    __shared__ double red[256];
    red[tid] = ls;
    __syncthreads();
    for (int s = 128; s > 0; s >>= 1) {
        if (tid < s) red[tid] += red[tid + s];
        __syncthreads();
    }
    if (tid == 0) atomicAdd(loss, red[0]);
}

// ---------------------------------------------------------------------------
// fin: scalars
__global__ void k_fin(const int* __restrict__ counts, const double* __restrict__ loss,
                      float* __restrict__ out) {
    int t = threadIdx.x;
    __shared__ double red[256];
    double h = 0.0;
    #pragma unroll
    for (int i = 0; i < 4; ++i) {
        double p = (double)counts[t + i * 256] / (double)N_ROWS;
        h += p * log(p + 1e-10);
    }
    red[t] = h;
    __syncthreads();
    for (int s = 128; s > 0; s >>= 1) {
        if (t < s) red[t] += red[t + s];
        __syncthreads();
    }
    if (t == 0) {
        out[OUT_PERP] = (float)exp(-red[0]);
        out[OUT_LOSS] = (float)((*loss) / (double)Q_SIZE * 1.25);
    }
}

// ---------------------------------------------------------------------------
extern "C" void kernel_launch(void* const* d_in, const int* in_sizes, int n_in,
                              void* d_out, int out_size, void* d_ws, size_t ws_size,
                              hipStream_t stream) {
    (void)in_sizes; (void)n_in; (void)out_size; (void)ws_size;
    const float* X = (const float*)d_in[0];
    const float* E = (const float*)d_in[1];
    float* out = (float*)d_out;
    char* ws = (char*)d_ws;

    double*    loss   = (double*)(ws + WS_LOSS);
    int*       rcnt   = (int*)(ws + WS_RCNT);
    float*     e2     = (float*)(ws + WS_E2);
    float*     e2p    = (float*)(ws + WS_E2P);
    int*       counts = (int*)(ws + WS_COUNTS);
    int*       idx_ws = (int*)(ws + WS_IDX);
    int*       rlist  = (int*)(ws + WS_RLIST);
    float*     Et     = (float*)(ws + WS_ET);
    _Float16*  Pp     = (_Float16*)(ws + WS_P);

    k_prep<<<1024, 256, 0, stream>>>(E, e2, e2p, Et, Pp, counts, loss, rcnt);
    k_main<<<N_ROWS / RPB, 256, 0, stream>>>(X, Pp, e2p, idx_ws, rlist, rcnt);
    k_refine<<<1024, 256, 0, stream>>>(X, Et, e2, rlist, rcnt, idx_ws);
    k_out<<<1024, 256, 0, stream>>>(X, E, idx_ws, out, counts, loss);
    k_fin<<<1, 256, 0, stream>>>(counts, loss, out);
}

// Round 20
// 165.855 us; speedup vs baseline: 1.2688x; 1.0342x over previous
//
#include <hip/hip_runtime.h>
#include <math.h>

#define N_ROWS   65536
#define DIM      256
#define KCODES   1024
#define Q_SIZE   (N_ROWS * DIM)          // 16777216
#define OUT_LOSS Q_SIZE
#define OUT_PERP (Q_SIZE + 1)
#define OUT_IDX  (Q_SIZE + 2)

// flag threshold in scaled-score units (s' = 2^20 * d2-units). Same as r8 (passed).
#define TAUP 200.0f

// ws layout (bytes)
#define WS_LOSS   0        // double
#define WS_RCNT   8        // int
#define WS_E2     16       // float[1024]  original units
#define WS_E2P    4112     // float[1024]  scaled by 2^20
#define WS_COUNTS 8208     // int[1024]
#define WS_IDX    12304    // int[65536]
#define WS_RLIST  274448   // int[65536]
#define WS_ET     536592   // float[262144]   E^T fp32 (refine)
#define WS_P      1585168  // _Float16[262144] packed f16(1024*E), tile-linear

typedef _Float16 half8 __attribute__((ext_vector_type(8)));
typedef _Float16 half4 __attribute__((ext_vector_type(4)));
typedef float    f32x4 __attribute__((ext_vector_type(4)));

#define ROWB 528    // LDS bytes per X row during A-load phase: 512 + 16 pad
#define RPB  128    // rows per block (r20: A-in-registers, 2x rows per B-byte)

// k_main LDS: [0,33792) X-staging region, REUSED as B dbuf [2][16384] after
// the A-register load phase; [33792,37888) e2p.
#define LDS_E2 33792

// ---------------------------------------------------------------------------
// prep: e2, e2p, Et (fp32 transpose, refine), packed P; zero accums.
// P layout (r20, tile-linear): tile T = codes [T*32,T*32+32), 32 tiles.
// chunk c = nt*8+kk (nt: 16-code half, kk: K-slice). Offset of half o:
//   o = ((T*16 + c)*64 + lane)*8 + j ; code = T*32+nt*16+(lane&15),
//   d = (lane>>4)*8 + kk*32 + j.  Each 1KB chunk is lane-linear (GLL-ready).
// grid 1024 x 256
__global__ void k_prep(const float* __restrict__ E, float* __restrict__ e2,
                       float* __restrict__ e2p, float* __restrict__ Et,
                       _Float16* __restrict__ P,
                       int* __restrict__ counts, double* __restrict__ loss,
                       int* __restrict__ rcnt) {
    int b = blockIdx.x, t = threadIdx.x;
    __shared__ double red[256];
    float v = E[b * DIM + t];
    red[t] = (double)v * (double)v;

    {   // packed B-stream write (tile-linear)
        int o    = b * 256 + t;
        int j    = o & 7;
        int lane = (o >> 3) & 63;
        int c    = (o >> 9) & 15;      // chunk within tile
        int T    = o >> 13;            // tile 0..31
        int nt = c >> 3, kk = c & 7;
        int code = T * 32 + nt * 16 + (lane & 15);
        int d    = (lane >> 4) * 8 + kk * 32 + j;
        P[o] = (_Float16)(E[code * DIM + d] * 1024.0f);   // exact scaling, RN
    }

    __syncthreads();
    for (int s = 128; s > 0; s >>= 1) {
        if (t < s) red[t] += red[t + s];
        __syncthreads();
    }
    if (t == 0) { e2[b] = (float)red[0]; e2p[b] = (float)(red[0] * 1048576.0); }

    int o = b * 256 + t;
    int d = o >> 10, k = o & 1023;
    Et[o] = E[k * DIM + d];

    if (b < 4) counts[b * 256 + t] = 0;
    if (b == 0 && t == 0) { *loss = 0.0; *rcnt = 0; }
}

// ---------------------------------------------------------------------------
// main (r20): A-in-registers GEMM. Block = 128 rows, 4 waves; wave w owns
// rows [w*32, w*32+32) (A = 64 VGPRs, loaded once via a 2-phase LDS stage)
// and computes ALL 1024 codes. B streams through a block-shared LDS double
// buffer: 32 tiles x 16KB, staged cooperatively with global_load_lds (r10-
// proven pattern), one __syncthreads per tile.
// WHY: r8-r19 collapse onto time ∝ per-CU B bytes (~45-50 GB/s/CU L1-miss
// path). Only rows-per-block cuts bytes/row: 8KB -> 4KB. Total B 512->256MB.
// Numerics: same xh*Eh product, same per-(row,code) fp32 accumulation order,
// same TAUP net — outputs bit-identical to r8-r19.
// OCCUPANCY NOTE (r4-r7,r16): never cap min-waves / 512-thr blocks — spills.
// grid 512 x 256
__global__ void __launch_bounds__(256)
k_main(const float* __restrict__ X, const _Float16* __restrict__ P,
       const float* __restrict__ e2p,
       int* __restrict__ idx_ws, int* __restrict__ rlist,
       int* __restrict__ rcnt) {
    __shared__ __align__(16) char sAll[37888];
    const int tid  = threadIdx.x;
    const int wid  = tid >> 6;
    const int lane = tid & 63;
    const int c16  = lane & 15;
    const int kg   = lane >> 4;
    const int rb   = blockIdx.x * RPB;

    char* sX = sAll;                    // X staging (phase region)
    char* sB = sAll;                    // B dbuf (reuses same region)
    const float* sE2 = (const float*)(sAll + LDS_E2);

    // stage e2p (1024 floats, 1 f32x4/thread)
    ((f32x4*)(sAll + LDS_E2))[tid] = ((const f32x4*)e2p)[tid];

    // ---- A-load phase 1: rows 0..63 -> LDS f16, waves 0,1 grab A regs ----
    {
        const f32x4* Xg = (const f32x4*)(X + (size_t)rb * DIM);
        #pragma unroll
        for (int it = 0; it < 16; ++it) {
            int f = it * 256 + tid;
            int row = f >> 6, d4 = f & 63;
            f32x4 v = __builtin_nontemporal_load(&Xg[(size_t)row * 64 + d4]);
            half4 hh = {(_Float16)v[0], (_Float16)v[1], (_Float16)v[2], (_Float16)v[3]};
            *(half4*)(sX + row * ROWB + d4 * 8) = hh;
        }
    }
    __syncthreads();
    half8 ar[2][8];
    if (wid < 2) {
        #pragma unroll
        for (int mt = 0; mt < 2; ++mt)
            #pragma unroll
            for (int kk = 0; kk < 8; ++kk)
                ar[mt][kk] = *(const half8*)(sX + (wid * 32 + mt * 16 + c16) * ROWB
                                             + kk * 64 + kg * 16);
    }
    __syncthreads();
    // ---- A-load phase 2: rows 64..127, waves 2,3 grab A regs ----
    {
        const f32x4* Xg = (const f32x4*)(X + (size_t)(rb + 64) * DIM);
        #pragma unroll
        for (int it = 0; it < 16; ++it) {
            int f = it * 256 + tid;
            int row = f >> 6, d4 = f & 63;
            f32x4 v = __builtin_nontemporal_load(&Xg[(size_t)row * 64 + d4]);
            half4 hh = {(_Float16)v[0], (_Float16)v[1], (_Float16)v[2], (_Float16)v[3]};
            *(half4*)(sX + row * ROWB + d4 * 8) = hh;
        }
    }
    __syncthreads();
    if (wid >= 2) {
        #pragma unroll
        for (int mt = 0; mt < 2; ++mt)
            #pragma unroll
            for (int kk = 0; kk < 8; ++kk)
                ar[mt][kk] = *(const half8*)(sX + ((wid - 2) * 32 + mt * 16 + c16) * ROWB
                                             + kk * 64 + kg * 16);
    }
    __syncthreads();   // X region now free -> becomes B double buffer

    // ---- B tile pipeline: wave w stages chunks [w*4, w*4+4) of each tile ----
#define STAGE(T)                                                                             \
    {                                                                                        \
        const char* src_ = (const char*)P + (size_t)(T) * 16384 + (size_t)(wid * 4) * 1024   \
                           + (size_t)lane * 16;                                              \
        char* dst_ = sB + ((T) & 1) * 16384 + (wid * 4) * 1024;                              \
        __builtin_amdgcn_global_load_lds((const __attribute__((address_space(1))) unsigned int*)(src_),          \
                                         (__attribute__((address_space(3))) unsigned int*)(dst_), 16, 0, 0);     \
        __builtin_amdgcn_global_load_lds((const __attribute__((address_space(1))) unsigned int*)(src_ + 1024),   \
                                         (__attribute__((address_space(3))) unsigned int*)(dst_ + 1024), 16, 0, 0);\
        __builtin_amdgcn_global_load_lds((const __attribute__((address_space(1))) unsigned int*)(src_ + 2048),   \
                                         (__attribute__((address_space(3))) unsigned int*)(dst_ + 2048), 16, 0, 0);\
        __builtin_amdgcn_global_load_lds((const __attribute__((address_space(1))) unsigned int*)(src_ + 3072),   \
                                         (__attribute__((address_space(3))) unsigned int*)(dst_ + 3072), 16, 0, 0);\
    }

    float tb1[8], tb2[8];
    int   ti1[8];
    #pragma unroll
    for (int i = 0; i < 8; ++i) { tb1[i] = 3.4e38f; tb2[i] = 3.4e38f; ti1[i] = 0; }

    f32x4 acc[2][2];

    STAGE(0);
    __syncthreads();

    #pragma unroll 2
    for (int T = 0; T < 32; ++T) {
        if (T < 31) STAGE(T + 1);

        #pragma unroll
        for (int mt = 0; mt < 2; ++mt)
            #pragma unroll
            for (int nt = 0; nt < 2; ++nt) acc[mt][nt] = 0.0f;

        const char* bbuf = sB + (T & 1) * 16384 + (size_t)lane * 16;
        #pragma unroll
        for (int kk = 0; kk < 8; ++kk) {
            half8 b0 = *(const half8*)(bbuf + (0 * 8 + kk) * 1024);
            half8 b1 = *(const half8*)(bbuf + (1 * 8 + kk) * 1024);
            acc[0][0] = __builtin_amdgcn_mfma_f32_16x16x32_f16(ar[0][kk], b0, acc[0][0], 0, 0, 0);
            acc[0][1] = __builtin_amdgcn_mfma_f32_16x16x32_f16(ar[0][kk], b1, acc[0][1], 0, 0, 0);
            acc[1][0] = __builtin_amdgcn_mfma_f32_16x16x32_f16(ar[1][kk], b0, acc[1][0], 0, 0, 0);
            acc[1][1] = __builtin_amdgcn_mfma_f32_16x16x32_f16(ar[1][kk], b1, acc[1][1], 0, 0, 0);
        }

        // epilogue: s' = e2' - 2048*dot', sorted-insert top-2 (med3 form)
        #pragma unroll
        for (int nt = 0; nt < 2; ++nt) {
            const int code = T * 32 + nt * 16 + c16;
            const float e2v = sE2[code];
            #pragma unroll
            for (int mt = 0; mt < 2; ++mt)
                #pragma unroll
                for (int r = 0; r < 4; ++r) {
                    float sc = fmaf(-2048.0f, acc[mt][nt][r], e2v);
                    int ix = mt * 4 + r;
                    tb2[ix] = __builtin_amdgcn_fmed3f(tb1[ix], tb2[ix], sc);
                    bool lt = sc < tb1[ix];
                    tb1[ix] = lt ? sc : tb1[ix];
                    ti1[ix] = lt ? code : ti1[ix];
                }
        }
        __syncthreads();   // tile T+1 staged & everyone past buf (T+1)&1
    }
#undef STAGE

    // ---- butterfly merge across the 16 c16-lanes; waves own disjoint rows ----
    #pragma unroll
    for (int ix = 0; ix < 8; ++ix) {
        float v1 = tb1[ix], v2 = tb2[ix];
        int   j1 = ti1[ix];
        #pragma unroll
        for (int m = 1; m < 16; m <<= 1) {
            float ov1 = __shfl_xor(v1, m, 64);
            int   oj1 = __shfl_xor(j1, m, 64);
            float ov2 = __shfl_xor(v2, m, 64);
            bool take = (ov1 < v1) || (ov1 == v1 && oj1 < j1);
            float losr = take ? v1 : ov1;
            v1 = take ? ov1 : v1;
            j1 = take ? oj1 : j1;
            v2 = fminf(fminf(v2, ov2), losr);
        }
        tb1[ix] = v1; tb2[ix] = v2; ti1[ix] = j1;
    }
    if (c16 == 0) {
        #pragma unroll
        for (int ix = 0; ix < 8; ++ix) {
            int row = wid * 32 + (ix >> 2) * 16 + kg * 4 + (ix & 3);
            int g = rb + row;
            idx_ws[g] = ti1[ix];
            if (tb2[ix] - tb1[ix] < TAUP) {
                int slot = atomicAdd(rcnt, 1);
                rlist[slot] = g;
            }
        }
    }
}

// ---------------------------------------------------------------------------
// refine: exact reference-fp32 replication, 4 rows per Et sweep, d-loop
// unrolled x4, grid 1024 (r12/r13-proven). fp64 accumulation order per
// accumulator UNCHANGED.
// grid 1024 x 256
__launch_bounds__(256, 1)
__global__ void k_refine(const float* __restrict__ X, const float* __restrict__ Et,
                         const float* __restrict__ e2,
                         const int* __restrict__ rlist, const int* __restrict__ rcnt,
                         int* __restrict__ idx_ws) {
    __shared__ float xs[4][256];
    __shared__ float sbv[4][256];
    __shared__ int   sbi[4][256];
    __shared__ float x2s[4];
    __shared__ int   rows[4];
    const int cnt = *rcnt;
    const int t = threadIdx.x;
    for (int base = blockIdx.x * 4; base < cnt; base += gridDim.x * 4) {
        __syncthreads();
        if (t < 4) {
            int e = base + t;
            rows[t] = rlist[e < cnt ? e : (cnt - 1)];
        }
        __syncthreads();
        ((float4*)xs[t >> 6])[t & 63] =
            ((const float4*)(X + (size_t)rows[t >> 6] * DIM))[t & 63];
        __syncthreads();
        if (t < 4) {
            double s = 0.0;
            for (int d = 0; d < DIM; ++d) { double xv = (double)xs[t][d]; s += xv * xv; }
            x2s[t] = (float)s;
        }
        __syncthreads();

        double a0[4], a1[4], a2[4], a3[4];
        #pragma unroll
        for (int r = 0; r < 4; ++r) { a0[r] = 0.0; a1[r] = 0.0; a2[r] = 0.0; a3[r] = 0.0; }
        #pragma unroll 4
        for (int d = 0; d < DIM; ++d) {
            double e0 = (double)Et[d * KCODES + t];
            double e1 = (double)Et[d * KCODES + 256 + t];
            double e2d = (double)Et[d * KCODES + 512 + t];
            double e3 = (double)Et[d * KCODES + 768 + t];
            #pragma unroll
            for (int r = 0; r < 4; ++r) {
                double xv = (double)xs[r][d];
                a0[r] += xv * e0;
                a1[r] += xv * e1;
                a2[r] += xv * e2d;
                a3[r] += xv * e3;
            }
        }

        const float eA = e2[t], eB = e2[256 + t], eC = e2[512 + t], eD = e2[768 + t];
        #pragma unroll
        for (int r = 0; r < 4; ++r) {
            float best = 3.4e38f; int bk = 0;
            float x2 = x2s[r];
            { float d2 = fmaf(-2.f, (float)a0[r], x2 + eA); if (d2 < best) { best = d2; bk = t; } }
            { float d2 = fmaf(-2.f, (float)a1[r], x2 + eB); if (d2 < best) { best = d2; bk = 256 + t; } }
            { float d2 = fmaf(-2.f, (float)a2[r], x2 + eC); if (d2 < best) { best = d2; bk = 512 + t; } }
            { float d2 = fmaf(-2.f, (float)a3[r], x2 + eD); if (d2 < best) { best = d2; bk = 768 + t; } }
            sbv[r][t] = best; sbi[r][t] = bk;
        }
        __syncthreads();
        {
            const int w = t >> 6, lane = t & 63;
            float v = sbv[w][lane];     int id = sbi[w][lane];
            #pragma unroll
            for (int c = 1; c < 4; ++c) {
                float ov = sbv[w][lane + 64 * c]; int oi = sbi[w][lane + 64 * c];
                if (ov < v || (ov == v && oi < id)) { v = ov; id = oi; }
            }
            #pragma unroll
            for (int m = 1; m < 64; m <<= 1) {
                float ov = __shfl_xor(v, m, 64);
                int   oi = __shfl_xor(id, m, 64);
                if (ov < v || (ov == v && oi < id)) { v = ov; id = oi; }
            }
            if (lane == 0 && base + w < cnt) idx_ws[rows[w]] = id;
        }
    }
}

// ---------------------------------------------------------------------------
// out: quantized rows, index output, loss, histogram. One fp64 atomic/block.
// grid 1024 x 256
__launch_bounds__(256)
__global__ void k_out(const float* __restrict__ X, const float* __restrict__ E,
                      const int* __restrict__ idx_ws, float* __restrict__ out,
                      int* __restrict__ counts, double* __restrict__ loss) {
    const int tid = threadIdx.x;
    const int w = tid >> 6, lane = tid & 63;
    const int rbase = blockIdx.x * 64;
    double ls = 0.0;
    #pragma unroll 4
    for (int it = 0; it < 16; ++it) {
        const int row = rbase + it * 4 + w;
        const int k = idx_ws[row];
        float4 q = ((const float4*)(E + (size_t)k * DIM))[lane];
        float4 x = ((const float4*)(X + (size_t)row * DIM))[lane];
        ((float4*)(out + (size_t)row * DIM))[lane] = q;
        double d0 = (double)q.x - (double)x.x;
        double d1 = (double)q.y - (double)x.y;
        double d2 = (double)q.z - (double)x.z;
        double d3 = (double)q.w - (double)x.w;
        ls += d0 * d0 + d1 * d1 + d2 * d2 + d3 * d3;
        if (lane == 0) {
            atomicAdd(&counts[k], 1);
            out[OUT_IDX + row] = (float)k;
        }
    }
    __shared__ double red[256];
    red[tid] = ls;
    __syncthreads();
    for (int s = 128; s > 0; s >>= 1) {
        if (tid < s) red[tid] += red[tid + s];
        __syncthreads();
    }
    if (tid == 0) atomicAdd(loss, red[0]);
}

// ---------------------------------------------------------------------------
// fin: scalars
__global__ void k_fin(const int* __restrict__ counts, const double* __restrict__ loss,
                      float* __restrict__ out) {
    int t = threadIdx.x;
    __shared__ double red[256];
    double h = 0.0;
    #pragma unroll
    for (int i = 0; i < 4; ++i) {
        double p = (double)counts[t + i * 256] / (double)N_ROWS;
        h += p * log(p + 1e-10);
    }
    red[t] = h;
    __syncthreads();
    for (int s = 128; s > 0; s >>= 1) {
        if (t < s) red[t] += red[t + s];
        __syncthreads();
    }
    if (t == 0) {
        out[OUT_PERP] = (float)exp(-red[0]);
        out[OUT_LOSS] = (float)((*loss) / (double)Q_SIZE * 1.25);
    }
}

// ---------------------------------------------------------------------------
extern "C" void kernel_launch(void* const* d_in, const int* in_sizes, int n_in,
                              void* d_out, int out_size, void* d_ws, size_t ws_size,
                              hipStream_t stream) {
    (void)in_sizes; (void)n_in; (void)out_size; (void)ws_size;
    const float* X = (const float*)d_in[0];
    const float* E = (const float*)d_in[1];
    float* out = (float*)d_out;
    char* ws = (char*)d_ws;

    double*    loss   = (double*)(ws + WS_LOSS);
    int*       rcnt   = (int*)(ws + WS_RCNT);
    float*     e2     = (float*)(ws + WS_E2);
    float*     e2p    = (float*)(ws + WS_E2P);
    int*       counts = (int*)(ws + WS_COUNTS);
    int*       idx_ws = (int*)(ws + WS_IDX);
    int*       rlist  = (int*)(ws + WS_RLIST);
    float*     Et     = (float*)(ws + WS_ET);
    _Float16*  Pp     = (_Float16*)(ws + WS_P);

    k_prep<<<1024, 256, 0, stream>>>(E, e2, e2p, Et, Pp, counts, loss, rcnt);
    k_main<<<N_ROWS / RPB, 256, 0, stream>>>(X, Pp, e2p, idx_ws, rlist, rcnt);
    k_refine<<<1024, 256, 0, stream>>>(X, Et, e2, rlist, rcnt, idx_ws);
    k_out<<<1024, 256, 0, stream>>>(X, E, idx_ws, out, counts, loss);
    k_fin<<<1, 256, 0, stream>>>(counts, loss, out);
}

// Round 21
// 165.388 us; speedup vs baseline: 1.2724x; 1.0028x over previous
//
#include <hip/hip_runtime.h>
#include <math.h>

#define N_ROWS   65536
#define DIM      256
#define KCODES   1024
#define Q_SIZE   (N_ROWS * DIM)          // 16777216
#define OUT_LOSS Q_SIZE
#define OUT_PERP (Q_SIZE + 1)
#define OUT_IDX  (Q_SIZE + 2)

// flag threshold in scaled-score units (s' = 2^20 * d2-units). Same as r8 (passed).
#define TAUP 200.0f

// ws layout (bytes)
#define WS_LOSS   0        // double
#define WS_RCNT   8        // int
#define WS_E2     16       // float[1024]  original units
#define WS_E2P    4112     // float[1024]  scaled by 2^20
#define WS_COUNTS 8208     // int[1024]
#define WS_IDX    12304    // int[65536]
#define WS_RLIST  274448   // int[65536]
#define WS_ET     536592   // float[262144]   E^T fp32 (refine)
#define WS_P      1585168  // _Float16[262144] packed f16(1024*E), tile-linear

typedef _Float16 half8 __attribute__((ext_vector_type(8)));
typedef _Float16 half4 __attribute__((ext_vector_type(4)));
typedef float    f32x4 __attribute__((ext_vector_type(4)));

#define ROWB 528    // LDS bytes per X row during A-load phase: 512 + 16 pad
#define RPB  128    // rows per block (r20 A-in-registers geometry)

// k_main LDS: [0,49152) = X-staging region (phase 1/2) REUSED as 3-slot B
// rotation buffer [3][16384]; [49152,53248) e2p.
#define LDS_E2 49152

// ---------------------------------------------------------------------------
// prep: e2, e2p, Et (fp32 transpose, refine), packed P; zero accums.
// P layout (tile-linear): tile T = codes [T*32,T*32+32), 32 tiles.
// chunk c = nt*8+kk. o = ((T*16+c)*64+lane)*8+j; code = T*32+nt*16+(lane&15),
// d = (lane>>4)*8 + kk*32 + j. Each 1KB chunk lane-linear (GLL-ready).
// grid 1024 x 256
__global__ void k_prep(const float* __restrict__ E, float* __restrict__ e2,
                       float* __restrict__ e2p, float* __restrict__ Et,
                       _Float16* __restrict__ P,
                       int* __restrict__ counts, double* __restrict__ loss,
                       int* __restrict__ rcnt) {
    int b = blockIdx.x, t = threadIdx.x;
    __shared__ double red[256];
    float v = E[b * DIM + t];
    red[t] = (double)v * (double)v;

    {   // packed B-stream write (tile-linear)
        int o    = b * 256 + t;
        int j    = o & 7;
        int lane = (o >> 3) & 63;
        int c    = (o >> 9) & 15;      // chunk within tile
        int T    = o >> 13;            // tile 0..31
        int nt = c >> 3, kk = c & 7;
        int code = T * 32 + nt * 16 + (lane & 15);
        int d    = (lane >> 4) * 8 + kk * 32 + j;
        P[o] = (_Float16)(E[code * DIM + d] * 1024.0f);   // exact scaling, RN
    }

    __syncthreads();
    for (int s = 128; s > 0; s >>= 1) {
        if (t < s) red[t] += red[t + s];
        __syncthreads();
    }
    if (t == 0) { e2[b] = (float)red[0]; e2p[b] = (float)(red[0] * 1048576.0); }

    int o = b * 256 + t;
    int d = o >> 10, k = o & 1023;
    Et[o] = E[k * DIM + d];

    if (b < 4) counts[b * 256 + t] = 0;
    if (b == 0 && t == 0) { *loss = 0.0; *rcnt = 0; }
}

// ---------------------------------------------------------------------------
// main (r21): r20 A-in-registers GEMM + counted-vmcnt raw-barrier pipeline.
// r20's per-tile __syncthreads lowered to s_waitcnt vmcnt(0) lgkmcnt(0) —
// a full drain of the prefetch queue at EVERY tile (~1000cyc x 32). Now:
// 3-slot B rotation; per tile: vmcnt(4) (drain only tile T, keep T+1 in
// flight) -> raw s_barrier -> STAGE(T+2) (slot safe: its readers were iter
// T-1, all waves completed that before this barrier) -> compute T.
// Numerics bit-identical to r8-r20.
// OCCUPANCY NOTE (r4-r7,r16): never cap min-waves / 512-thr blocks — spills.
// grid 512 x 256
__global__ void __launch_bounds__(256)
k_main(const float* __restrict__ X, const _Float16* __restrict__ P,
       const float* __restrict__ e2p,
       int* __restrict__ idx_ws, int* __restrict__ rlist,
       int* __restrict__ rcnt) {
    __shared__ __align__(16) char sAll[53248];
    const int tid  = threadIdx.x;
    const int wid  = tid >> 6;
    const int lane = tid & 63;
    const int c16  = lane & 15;
    const int kg   = lane >> 4;
    const int rb   = blockIdx.x * RPB;

    char* sX = sAll;                    // X staging (phase region)
    char* sB = sAll;                    // B 3-slot rotation (reuses region)
    const float* sE2 = (const float*)(sAll + LDS_E2);

    // stage e2p (1024 floats, 1 f32x4/thread)
    ((f32x4*)(sAll + LDS_E2))[tid] = ((const f32x4*)e2p)[tid];

    // ---- A-load phase 1: rows 0..63 -> LDS f16, waves 0,1 grab A regs ----
    {
        const f32x4* Xg = (const f32x4*)(X + (size_t)rb * DIM);
        #pragma unroll
        for (int it = 0; it < 16; ++it) {
            int f = it * 256 + tid;
            int row = f >> 6, d4 = f & 63;
            f32x4 v = __builtin_nontemporal_load(&Xg[(size_t)row * 64 + d4]);
            half4 hh = {(_Float16)v[0], (_Float16)v[1], (_Float16)v[2], (_Float16)v[3]};
            *(half4*)(sX + row * ROWB + d4 * 8) = hh;
        }
    }
    __syncthreads();
    half8 ar[2][8];
    if (wid < 2) {
        #pragma unroll
        for (int mt = 0; mt < 2; ++mt)
            #pragma unroll
            for (int kk = 0; kk < 8; ++kk)
                ar[mt][kk] = *(const half8*)(sX + (wid * 32 + mt * 16 + c16) * ROWB
                                             + kk * 64 + kg * 16);
    }
    __syncthreads();
    // ---- A-load phase 2: rows 64..127, waves 2,3 grab A regs ----
    {
        const f32x4* Xg = (const f32x4*)(X + (size_t)(rb + 64) * DIM);
        #pragma unroll
        for (int it = 0; it < 16; ++it) {
            int f = it * 256 + tid;
            int row = f >> 6, d4 = f & 63;
            f32x4 v = __builtin_nontemporal_load(&Xg[(size_t)row * 64 + d4]);
            half4 hh = {(_Float16)v[0], (_Float16)v[1], (_Float16)v[2], (_Float16)v[3]};
            *(half4*)(sX + row * ROWB + d4 * 8) = hh;
        }
    }
    __syncthreads();
    if (wid >= 2) {
        #pragma unroll
        for (int mt = 0; mt < 2; ++mt)
            #pragma unroll
            for (int kk = 0; kk < 8; ++kk)
                ar[mt][kk] = *(const half8*)(sX + ((wid - 2) * 32 + mt * 16 + c16) * ROWB
                                             + kk * 64 + kg * 16);
    }
    __syncthreads();   // full drain: X region free; vmcnt==0 -> counts only B

    // ---- B tile pipeline: wave w stages chunks [w*4, w*4+4); slot = T%3 ----
#define STAGE(T)                                                                             \
    {                                                                                        \
        const char* src_ = (const char*)P + (size_t)(T) * 16384 + (size_t)(wid * 4) * 1024   \
                           + (size_t)lane * 16;                                              \
        char* dst_ = sB + ((T) % 3) * 16384 + (wid * 4) * 1024;                              \
        __builtin_amdgcn_global_load_lds((const __attribute__((address_space(1))) unsigned int*)(src_),          \
                                         (__attribute__((address_space(3))) unsigned int*)(dst_), 16, 0, 0);     \
        __builtin_amdgcn_global_load_lds((const __attribute__((address_space(1))) unsigned int*)(src_ + 1024),   \
                                         (__attribute__((address_space(3))) unsigned int*)(dst_ + 1024), 16, 0, 0);\
        __builtin_amdgcn_global_load_lds((const __attribute__((address_space(1))) unsigned int*)(src_ + 2048),   \
                                         (__attribute__((address_space(3))) unsigned int*)(dst_ + 2048), 16, 0, 0);\
        __builtin_amdgcn_global_load_lds((const __attribute__((address_space(1))) unsigned int*)(src_ + 3072),   \
                                         (__attribute__((address_space(3))) unsigned int*)(dst_ + 3072), 16, 0, 0);\
    }
#define SB0 __builtin_amdgcn_sched_barrier(0)

    float tb1[8], tb2[8];
    int   ti1[8];
    #pragma unroll
    for (int i = 0; i < 8; ++i) { tb1[i] = 3.4e38f; tb2[i] = 3.4e38f; ti1[i] = 0; }

    f32x4 acc[2][2];

    STAGE(0); STAGE(1);
    SB0;

    #pragma unroll 2
    for (int T = 0; T < 32; ++T) {
        // drain ONLY tile T's 4 loads (T+1 stays in flight); raw barrier
        if (T <= 30) { asm volatile("s_waitcnt vmcnt(4)" ::: "memory"); }
        else         { asm volatile("s_waitcnt vmcnt(0)" ::: "memory"); }
        SB0;
        __builtin_amdgcn_s_barrier();   // all waves' tile-T loads landed;
        SB0;                            // all waves finished iter T-1 reads
        if (T < 30) STAGE(T + 2);       // slot (T+2)%3: safe to overwrite
        SB0;

        #pragma unroll
        for (int mt = 0; mt < 2; ++mt)
            #pragma unroll
            for (int nt = 0; nt < 2; ++nt) acc[mt][nt] = 0.0f;

        const char* bbuf = sB + (T % 3) * 16384 + (size_t)lane * 16;
        #pragma unroll
        for (int kk = 0; kk < 8; ++kk) {
            half8 b0 = *(const half8*)(bbuf + (0 * 8 + kk) * 1024);
            half8 b1 = *(const half8*)(bbuf + (1 * 8 + kk) * 1024);
            acc[0][0] = __builtin_amdgcn_mfma_f32_16x16x32_f16(ar[0][kk], b0, acc[0][0], 0, 0, 0);
            acc[0][1] = __builtin_amdgcn_mfma_f32_16x16x32_f16(ar[0][kk], b1, acc[0][1], 0, 0, 0);
            acc[1][0] = __builtin_amdgcn_mfma_f32_16x16x32_f16(ar[1][kk], b0, acc[1][0], 0, 0, 0);
            acc[1][1] = __builtin_amdgcn_mfma_f32_16x16x32_f16(ar[1][kk], b1, acc[1][1], 0, 0, 0);
        }

        // epilogue: s' = e2' - 2048*dot', sorted-insert top-2 (med3 form)
        #pragma unroll
        for (int nt = 0; nt < 2; ++nt) {
            const int code = T * 32 + nt * 16 + c16;
            const float e2v = sE2[code];
            #pragma unroll
            for (int mt = 0; mt < 2; ++mt)
                #pragma unroll
                for (int r = 0; r < 4; ++r) {
                    float sc = fmaf(-2048.0f, acc[mt][nt][r], e2v);
                    int ix = mt * 4 + r;
                    tb2[ix] = __builtin_amdgcn_fmed3f(tb1[ix], tb2[ix], sc);
                    bool lt = sc < tb1[ix];
                    tb1[ix] = lt ? sc : tb1[ix];
                    ti1[ix] = lt ? code : ti1[ix];
                }
        }
        SB0;   // keep ds_reads/MFMA of tile T before next iteration's barrier
    }
#undef STAGE
#undef SB0

    // ---- butterfly merge across the 16 c16-lanes; waves own disjoint rows ----
    #pragma unroll
    for (int ix = 0; ix < 8; ++ix) {
        float v1 = tb1[ix], v2 = tb2[ix];
        int   j1 = ti1[ix];
        #pragma unroll
        for (int m = 1; m < 16; m <<= 1) {
            float ov1 = __shfl_xor(v1, m, 64);
            int   oj1 = __shfl_xor(j1, m, 64);
            float ov2 = __shfl_xor(v2, m, 64);
            bool take = (ov1 < v1) || (ov1 == v1 && oj1 < j1);
            float losr = take ? v1 : ov1;
            v1 = take ? ov1 : v1;
            j1 = take ? oj1 : j1;
            v2 = fminf(fminf(v2, ov2), losr);
        }
        tb1[ix] = v1; tb2[ix] = v2; ti1[ix] = j1;
    }
    if (c16 == 0) {
        #pragma unroll
        for (int ix = 0; ix < 8; ++ix) {
            int row = wid * 32 + (ix >> 2) * 16 + kg * 4 + (ix & 3);
            int g = rb + row;
            idx_ws[g] = ti1[ix];
            if (tb2[ix] - tb1[ix] < TAUP) {
                int slot = atomicAdd(rcnt, 1);
                rlist[slot] = g;
            }
        }
    }
}

// ---------------------------------------------------------------------------
// refine: exact reference-fp32 replication, 4 rows per Et sweep, d-loop
// unrolled x4, grid 1024 (r12/r13-proven). fp64 accumulation order per
// accumulator UNCHANGED.
// grid 1024 x 256
__launch_bounds__(256, 1)
__global__ void k_refine(const float* __restrict__ X, const float* __restrict__ Et,
                         const float* __restrict__ e2,
                         const int* __restrict__ rlist, const int* __restrict__ rcnt,
                         int* __restrict__ idx_ws) {
    __shared__ float xs[4][256];
    __shared__ float sbv[4][256];
    __shared__ int   sbi[4][256];
    __shared__ float x2s[4];
    __shared__ int   rows[4];
    const int cnt = *rcnt;
    const int t = threadIdx.x;
    for (int base = blockIdx.x * 4; base < cnt; base += gridDim.x * 4) {
        __syncthreads();
        if (t < 4) {
            int e = base + t;
            rows[t] = rlist[e < cnt ? e : (cnt - 1)];
        }
        __syncthreads();
        ((float4*)xs[t >> 6])[t & 63] =
            ((const float4*)(X + (size_t)rows[t >> 6] * DIM))[t & 63];
        __syncthreads();
        if (t < 4) {
            double s = 0.0;
            for (int d = 0; d < DIM; ++d) { double xv = (double)xs[t][d]; s += xv * xv; }
            x2s[t] = (float)s;
        }
        __syncthreads();

        double a0[4], a1[4], a2[4], a3[4];
        #pragma unroll
        for (int r = 0; r < 4; ++r) { a0[r] = 0.0; a1[r] = 0.0; a2[r] = 0.0; a3[r] = 0.0; }
        #pragma unroll 4
        for (int d = 0; d < DIM; ++d) {
            double e0 = (double)Et[d * KCODES + t];
            double e1 = (double)Et[d * KCODES + 256 + t];
            double e2d = (double)Et[d * KCODES + 512 + t];
            double e3 = (double)Et[d * KCODES + 768 + t];
            #pragma unroll
            for (int r = 0; r < 4; ++r) {
                double xv = (double)xs[r][d];
                a0[r] += xv * e0;
                a1[r] += xv * e1;
                a2[r] += xv * e2d;
                a3[r] += xv * e3;
            }
        }

        const float eA = e2[t], eB = e2[256 + t], eC = e2[512 + t], eD = e2[768 + t];
        #pragma unroll
        for (int r = 0; r < 4; ++r) {
            float best = 3.4e38f; int bk = 0;
            float x2 = x2s[r];
            { float d2 = fmaf(-2.f, (float)a0[r], x2 + eA); if (d2 < best) { best = d2; bk = t; } }
            { float d2 = fmaf(-2.f, (float)a1[r], x2 + eB); if (d2 < best) { best = d2; bk = 256 + t; } }
            { float d2 = fmaf(-2.f, (float)a2[r], x2 + eC); if (d2 < best) { best = d2; bk = 512 + t; } }
            { float d2 = fmaf(-2.f, (float)a3[r], x2 + eD); if (d2 < best) { best = d2; bk = 768 + t; } }
            sbv[r][t] = best; sbi[r][t] = bk;
        }
        __syncthreads();
        {
            const int w = t >> 6, lane = t & 63;
            float v = sbv[w][lane];     int id = sbi[w][lane];
            #pragma unroll
            for (int c = 1; c < 4; ++c) {
                float ov = sbv[w][lane + 64 * c]; int oi = sbi[w][lane + 64 * c];
                if (ov < v || (ov == v && oi < id)) { v = ov; id = oi; }
            }
            #pragma unroll
            for (int m = 1; m < 64; m <<= 1) {
                float ov = __shfl_xor(v, m, 64);
                int   oi = __shfl_xor(id, m, 64);
                if (ov < v || (ov == v && oi < id)) { v = ov; id = oi; }
            }
            if (lane == 0 && base + w < cnt) idx_ws[rows[w]] = id;
        }
    }
}

// ---------------------------------------------------------------------------
// out: quantized rows, index output, loss, histogram. One fp64 atomic/block.
// grid 1024 x 256
__launch_bounds__(256)
__global__ void k_out(const float* __restrict__ X, const float* __restrict__ E,
                      const int* __restrict__ idx_ws, float* __restrict__ out,
                      int* __restrict__ counts, double* __restrict__ loss) {
    const int tid = threadIdx.x;
    const int w = tid >> 6, lane = tid & 63;
    const int rbase = blockIdx.x * 64;
    double ls = 0.0;
    #pragma unroll 4
    for (int it = 0; it < 16; ++it) {
        const int row = rbase + it * 4 + w;
        const int k = idx_ws[row];
        float4 q = ((const float4*)(E + (size_t)k * DIM))[lane];
        float4 x = ((const float4*)(X + (size_t)row * DIM))[lane];
        ((float4*)(out + (size_t)row * DIM))[lane] = q;
        double d0 = (double)q.x - (double)x.x;
        double d1 = (double)q.y - (double)x.y;
        double d2 = (double)q.z - (double)x.z;
        double d3 = (double)q.w - (double)x.w;
        ls += d0 * d0 + d1 * d1 + d2 * d2 + d3 * d3;
        if (lane == 0) {
            atomicAdd(&counts[k], 1);
            out[OUT_IDX + row] = (float)k;
        }
    }
    __shared__ double red[256];
    red[tid] = ls;
    __syncthreads();
    for (int s = 128; s > 0; s >>= 1) {
        if (tid < s) red[tid] += red[tid + s];
        __syncthreads();
    }
    if (tid == 0) atomicAdd(loss, red[0]);
}

// ---------------------------------------------------------------------------
// fin: scalars
__global__ void k_fin(const int* __restrict__ counts, const double* __restrict__ loss,
                      float* __restrict__ out) {
    int t = threadIdx.x;
    __shared__ double red[256];
    double h = 0.0;
    #pragma unroll
    for (int i = 0; i < 4; ++i) {
        double p = (double)counts[t + i * 256] / (double)N_ROWS;
        h += p * log(p + 1e-10);
    }
    red[t] = h;
    __syncthreads();
    for (int s = 128; s > 0; s >>= 1) {
        if (t < s) red[t] += red[t + s];
        __syncthreads();
    }
    if (t == 0) {
        out[OUT_PERP] = (float)exp(-red[0]);
        out[OUT_LOSS] = (float)((*loss) / (double)Q_SIZE * 1.25);
    }
}

// ---------------------------------------------------------------------------
extern "C" void kernel_launch(void* const* d_in, const int* in_sizes, int n_in,
                              void* d_out, int out_size, void* d_ws, size_t ws_size,
                              hipStream_t stream) {
    (void)in_sizes; (void)n_in; (void)out_size; (void)ws_size;
    const float* X = (const float*)d_in[0];
    const float* E = (const float*)d_in[1];
    float* out = (float*)d_out;
    char* ws = (char*)d_ws;

    double*    loss   = (double*)(ws + WS_LOSS);
    int*       rcnt   = (int*)(ws + WS_RCNT);
    float*     e2     = (float*)(ws + WS_E2);
    float*     e2p    = (float*)(ws + WS_E2P);
    int*       counts = (int*)(ws + WS_COUNTS);
    int*       idx_ws = (int*)(ws + WS_IDX);
    int*       rlist  = (int*)(ws + WS_RLIST);
    float*     Et     = (float*)(ws + WS_ET);
    _Float16*  Pp     = (_Float16*)(ws + WS_P);

    k_prep<<<1024, 256, 0, stream>>>(E, e2, e2p, Et, Pp, counts, loss, rcnt);
    k_main<<<N_ROWS / RPB, 256, 0, stream>>>(X, Pp, e2p, idx_ws, rlist, rcnt);
    k_refine<<<1024, 256, 0, stream>>>(X, Et, e2, rlist, rcnt, idx_ws);
    k_out<<<1024, 256, 0, stream>>>(X, E, idx_ws, out, counts, loss);
    k_fin<<<1, 256, 0, stream>>>(counts, loss, out);
}